// Round 3
// baseline (383.993 us; speedup 1.0000x reference)
//
#include <hip/hip_runtime.h>

#define EPS 1e-6f
#define LN2F 0.69314718055994530942f

struct RunStats { int len, pre, suf, mx; };

__device__ inline RunStats rcombine(const RunStats& a, const RunStats& b) {
    RunStats r;
    r.len = a.len + b.len;
    r.pre = (a.pre == a.len) ? (a.len + b.pre) : a.pre;
    r.suf = (b.suf == b.len) ? (b.len + a.suf) : b.suf;
    r.mx  = max(max(a.mx, b.mx), a.suf + b.pre);
    return r;
}

// One block (256 threads = 4 waves) per row of N=4096.
// Wave w owns contiguous [w*1024, (w+1)*1024). Chunk q (256 elems): lane i
// loads float4 at chunk + i*4 -> fully coalesced 1KB per wave instruction.
// Correctness bits are gathered with __ballot per float4 component: mask
// m[q][c] bit i  <->  element q*256 + 4*i + c (interleaved order). All run
// statistics are computed on these wave-uniform masks in SGPRs (scalar pipe),
// so the cross-lane streak cost is ~zero VALU.
__global__ __launch_bounds__(256) void row_kernel(
        const float* __restrict__ yp, const float* __restrict__ yt,
        const float* __restrict__ dw,
        float* __restrict__ row_wbce, int* __restrict__ row_streak) {
    const int row  = blockIdx.x;
    const int lane = threadIdx.x & 63;
    const int wave = threadIdx.x >> 6;
    const long base = (long)row * 4096 + wave * 1024 + lane * 4;

    const float4* pp = (const float4*)(yp + base);
    const float4* tp = (const float4*)(yt + base);
    const float4* wp = (const float4*)(dw + base);

    // Hoist all 12 independent loads (same base VGPR pair + imm offsets).
    float4 P[4], T[4], W[4];
    #pragma unroll
    for (int q = 0; q < 4; ++q) {
        P[q] = pp[q * 64];   // +256 floats per chunk
        T[q] = tp[q * 64];
        W[q] = wp[q * 64];
    }

    float sum = 0.0f;                 // accumulates w * log2(selected)
    unsigned long long m[4][4];       // [chunk][component] correctness ballots
    #pragma unroll
    for (int q = 0; q < 4; ++q) {
        const float pv[4] = {P[q].x, P[q].y, P[q].z, P[q].w};
        const float tv[4] = {T[q].x, T[q].y, T[q].z, T[q].w};
        const float wv[4] = {W[q].x, W[q].y, W[q].z, W[q].w};
        #pragma unroll
        for (int c = 0; c < 4; ++c) {
            const bool tb = tv[c] != 0.0f;                     // y_true is 0/1
            const float sel = tb ? pv[c] : 1.0f - pv[c];
            sum = fmaf(wv[c], __log2f(sel + EPS), sum);
            const bool correct = (pv[c] > 0.5f) == tb;
            m[q][c] = __ballot(correct);
        }
    }

    // ---- run stats over the wave's 1024-bit sequence (all wave-uniform) ----
    // prefix run of 1s
    int pre;
    {
        int j = 0;
        while (j < 4 && (m[j][0] & m[j][1] & m[j][2] & m[j][3]) == ~0ULL) ++j;
        if (j == 4) pre = 1024;
        else {
            int best = 1 << 30;
            for (int c = 0; c < 4; ++c) {
                unsigned long long z = ~m[j][c];
                if (z) best = min(best, 4 * (int)__builtin_ctzll(z) + c);
            }
            pre = j * 256 + best;   // position of first 0 == # leading 1s
        }
    }
    // suffix run of 1s
    int suf;
    {
        int j = 3;
        while (j >= 0 && (m[j][0] & m[j][1] & m[j][2] & m[j][3]) == ~0ULL) --j;
        if (j < 0) suf = 1024;
        else {
            int last = -1;
            for (int c = 0; c < 4; ++c) {
                unsigned long long z = ~m[j][c];
                if (z) last = max(last, 4 * (63 - (int)__builtin_clzll(z)) + c);
            }
            suf = (3 - j) * 256 + (255 - last);
        }
    }
    // max run: iterate x &= (x << 1) on the interleaved representation.
    // seq<<1: comp c>0 <- comp c-1; comp 0 <- (comp3 << 1) | carry from chunk j-1.
    int mx = 0;
    {
        unsigned long long x[4][4];
        unsigned long long any = 0;
        for (int j = 0; j < 4; ++j)
            for (int c = 0; c < 4; ++c) { x[j][c] = m[j][c]; any |= m[j][c]; }
        while (any) {
            ++mx;
            any = 0;
            for (int j = 3; j >= 0; --j) {
                const unsigned long long n0 =
                    (x[j][3] << 1) | (j ? (x[j - 1][3] >> 63) : 0ULL);
                x[j][3] &= x[j][2];
                x[j][2] &= x[j][1];
                x[j][1] &= x[j][0];
                x[j][0] &= n0;
                any |= x[j][0] | x[j][1] | x[j][2] | x[j][3];
            }
        }
    }

    // wbce wave sum (commutative butterfly to lane 0)
    #pragma unroll
    for (int off = 32; off; off >>= 1) sum += __shfl_down(sum, off);

    __shared__ RunStats sstat[4];
    __shared__ float ssum[4];
    if (lane == 0) {
        RunStats g; g.len = 1024; g.pre = pre; g.suf = suf; g.mx = mx;
        sstat[wave] = g; ssum[wave] = sum;
    }
    __syncthreads();
    if (threadIdx.x == 0) {
        RunStats r = rcombine(rcombine(sstat[0], sstat[1]), rcombine(sstat[2], sstat[3]));
        row_wbce[row]   = -LN2F * (ssum[0] + ssum[1] + ssum[2] + ssum[3]);
        row_streak[row] = r.mx;
    }
}

__global__ __launch_bounds__(1024) void finalize_kernel(
        const float* __restrict__ row_wbce, const int* __restrict__ row_streak,
        int rows, float* __restrict__ out) {
    double s = 0.0;
    long long st = 0;
    for (int i = threadIdx.x; i < rows; i += 1024) {
        s  += (double)row_wbce[i];
        st += (long long)row_streak[i];
    }
    __shared__ double sd[1024];
    __shared__ long long sl[1024];
    sd[threadIdx.x] = s; sl[threadIdx.x] = st;
    __syncthreads();
    for (int o = 512; o; o >>= 1) {
        if (threadIdx.x < o) {
            sd[threadIdx.x] += sd[threadIdx.x + o];
            sl[threadIdx.x] += sl[threadIdx.x + o];
        }
        __syncthreads();
    }
    if (threadIdx.x == 0) {
        const double total = (double)rows * 4096.0;
        const double wbce = sd[0] / total;
        const double cwl  = 1.0 - (double)sl[0] / total;
        out[0] = (float)(0.5 * wbce + 0.5 * cwl);
    }
}

extern "C" void kernel_launch(void* const* d_in, const int* in_sizes, int n_in,
                              void* d_out, int out_size, void* d_ws, size_t ws_size,
                              hipStream_t stream) {
    const float* yp = (const float*)d_in[0];
    const float* yt = (const float*)d_in[1];
    const float* dw = (const float*)d_in[2];
    float* out = (float*)d_out;

    const int rows = in_sizes[0] / 4096;   // 8192
    float* row_wbce   = (float*)d_ws;
    int*   row_streak = (int*)((char*)d_ws + (size_t)rows * sizeof(float));

    row_kernel<<<rows, 256, 0, stream>>>(yp, yt, dw, row_wbce, row_streak);
    finalize_kernel<<<1, 1024, 0, stream>>>(row_wbce, row_streak, rows, out);
}

// Round 4
// 348.666 us; speedup vs baseline: 1.1013x; 1.1013x over previous
//
#include <hip/hip_runtime.h>

#define EPS 1e-6f
#define LN2F 0.69314718055994530942f

struct RunStats { int len, pre, suf, mx; };

__device__ inline RunStats rcombine(const RunStats& a, const RunStats& b) {
    RunStats r;
    r.len = a.len + b.len;
    r.pre = (a.pre == a.len) ? (a.len + b.pre) : a.pre;
    r.suf = (b.suf == b.len) ? (b.len + a.suf) : b.suf;
    r.mx  = max(max(a.mx, b.mx), a.suf + b.pre);
    return r;
}

// One block (256 threads = 4 waves) per row of N=4096.
// Wave w owns contiguous [w*1024, (w+1)*1024). Chunk q (256 elems): lane i
// loads float4 at chunk + 4i -> fully coalesced 1KB per wave instruction.
// Streak bits: lane's 4 elements per chunk are contiguous -> one correctness
// nibble per chunk; a 1-dword-per-lane LDS transpose hands lane j the 16
// sequence-ordered bits for elements [ (j>>4)*256 + 16*(j&15), +16 ), then a
// single packed shuffle tree per wave reduces run stats. No spill-prone
// arrays, no dynamic loops.
__global__ __launch_bounds__(256) void row_kernel(
        const float* __restrict__ yp, const float* __restrict__ yt,
        const float* __restrict__ dw,
        float* __restrict__ row_wbce, int* __restrict__ row_streak) {
    const int row  = blockIdx.x;
    const int lane = threadIdx.x & 63;
    const int wave = threadIdx.x >> 6;
    const long base = (long)row * 4096 + wave * 1024 + lane * 4;

    const float4* pp = (const float4*)(yp + base);
    const float4* tp = (const float4*)(yt + base);
    const float4* wp = (const float4*)(dw + base);

    // Hoist all 12 independent coalesced loads (max loads in flight).
    float4 P[4], T[4], W[4];
    #pragma unroll
    for (int q = 0; q < 4; ++q) {
        P[q] = pp[q * 64];   // +256 floats per chunk
        T[q] = tp[q * 64];
        W[q] = wp[q * 64];
    }

    float sum = 0.0f;        // accumulates w * log2(selected)
    unsigned nibs = 0;       // byte q = correctness nibble of chunk q
    #pragma unroll
    for (int q = 0; q < 4; ++q) {
        const float pv[4] = {P[q].x, P[q].y, P[q].z, P[q].w};
        const float tv[4] = {T[q].x, T[q].y, T[q].z, T[q].w};
        const float wv[4] = {W[q].x, W[q].y, W[q].z, W[q].w};
        #pragma unroll
        for (int c = 0; c < 4; ++c) {
            const bool tb = tv[c] != 0.0f;                   // y_true is 0/1
            const float sel = tb ? pv[c] : 1.0f - pv[c];
            sum = fmaf(wv[c], __log2f(sel + EPS), sum);
            const bool correct = (pv[c] > 0.5f) == tb;
            nibs |= (unsigned)correct << (8 * q + c);
        }
    }

    // ---- LDS nibble transpose: 1 dword write + 1 b128 broadcast read ----
    __shared__ unsigned nibbuf[256];           // 64 dwords per wave
    nibbuf[wave * 64 + lane] = nibs;
    __syncthreads();
    const uint4 d = *(const uint4*)&nibbuf[wave * 64 + 4 * (lane & 15)];
    const int qs = (lane >> 4) * 8;            // byte shift selecting chunk
    const unsigned mask = ((d.x >> qs) & 0xFu)
                        | (((d.y >> qs) & 0xFu) << 4)
                        | (((d.z >> qs) & 0xFu) << 8)
                        | (((d.w >> qs) & 0xFu) << 12);

    // ---- per-lane run stats over the 16-bit mask (bit0 = first element) ----
    const int pre = __builtin_ctz(~mask);            // 16 iff mask==0xffff
    const int suf = __builtin_clz(~(mask << 16));    // trailing-run via top bits
    // max run: fixed-cost doubling ladder + greedy binary extension.
    int mx;
    {
        const unsigned p1 = mask;
        const unsigned p2 = p1 & (p1 << 1);   // bit i => run >= 2 ending at i
        const unsigned p4 = p2 & (p2 << 2);   // run >= 4
        const unsigned p8 = p4 & (p4 << 4);   // run >= 8
        unsigned z; int len;
        if (p8)      { z = p8; len = 8; }
        else if (p4) { z = p4; len = 4; }
        else if (p2) { z = p2; len = 2; }
        else         { z = p1; len = 1; }
        { const unsigned t = (z << 8) & p8; if (t) { z = t; len += 8; } }
        { const unsigned t = (z << 4) & p4; if (t) { z = t; len += 4; } }
        { const unsigned t = (z << 2) & p2; if (t) { z = t; len += 2; } }
        { const unsigned t = (z << 1) & p1; if (t) { z = t; len += 1; } }
        mx = mask ? len : 0;
    }

    // wbce wave sum (commutative butterfly)
    #pragma unroll
    for (int off = 32; off; off >>= 1) sum += __shfl_down(sum, off);

    // ordered wave reduce of (pre,suf,mx): 5 packed 10-bit steps (fields <=512),
    // then a final unpacked step (fields may reach 1024). Lane 0 valid.
    int packed = pre | (suf << 10) | (mx << 20);
    int alen = 16;
    #pragma unroll
    for (int off = 1; off < 32; off <<= 1) {
        const int o = __shfl_down(packed, off);
        const int apre = packed & 1023, asuf = (packed >> 10) & 1023, amx = packed >> 20;
        const int bpre = o & 1023,      bsuf = (o >> 10) & 1023,      bmx = o >> 20;
        const int npre = (apre == alen) ? (alen + bpre) : apre;
        const int nsuf = (bsuf == alen) ? (alen + asuf) : bsuf;
        const int nmx  = max(max(amx, bmx), asuf + bpre);
        packed = npre | (nsuf << 10) | (nmx << 20);
        alen <<= 1;
    }
    RunStats g;
    {   // final step: off = 32, alen = 512
        const int o = __shfl_down(packed, 32);
        const int apre = packed & 1023, asuf = (packed >> 10) & 1023, amx = packed >> 20;
        const int bpre = o & 1023,      bsuf = (o >> 10) & 1023,      bmx = o >> 20;
        g.len = 1024;
        g.pre = (apre == 512) ? (512 + bpre) : apre;
        g.suf = (bsuf == 512) ? (512 + asuf) : bsuf;
        g.mx  = max(max(amx, bmx), asuf + bpre);
    }

    __shared__ RunStats sstat[4];
    __shared__ float ssum[4];
    if (lane == 0) { sstat[wave] = g; ssum[wave] = sum; }
    __syncthreads();
    if (threadIdx.x == 0) {
        RunStats r = rcombine(rcombine(sstat[0], sstat[1]), rcombine(sstat[2], sstat[3]));
        row_wbce[row]   = -LN2F * (ssum[0] + ssum[1] + ssum[2] + ssum[3]);
        row_streak[row] = r.mx;
    }
}

__global__ __launch_bounds__(1024) void finalize_kernel(
        const float* __restrict__ row_wbce, const int* __restrict__ row_streak,
        int rows, float* __restrict__ out) {
    double s = 0.0;
    long long st = 0;
    for (int i = threadIdx.x; i < rows; i += 1024) {
        s  += (double)row_wbce[i];
        st += (long long)row_streak[i];
    }
    __shared__ double sd[1024];
    __shared__ long long sl[1024];
    sd[threadIdx.x] = s; sl[threadIdx.x] = st;
    __syncthreads();
    for (int o = 512; o; o >>= 1) {
        if (threadIdx.x < o) {
            sd[threadIdx.x] += sd[threadIdx.x + o];
            sl[threadIdx.x] += sl[threadIdx.x + o];
        }
        __syncthreads();
    }
    if (threadIdx.x == 0) {
        const double total = (double)rows * 4096.0;
        const double wbce = sd[0] / total;
        const double cwl  = 1.0 - (double)sl[0] / total;
        out[0] = (float)(0.5 * wbce + 0.5 * cwl);
    }
}

extern "C" void kernel_launch(void* const* d_in, const int* in_sizes, int n_in,
                              void* d_out, int out_size, void* d_ws, size_t ws_size,
                              hipStream_t stream) {
    const float* yp = (const float*)d_in[0];
    const float* yt = (const float*)d_in[1];
    const float* dw = (const float*)d_in[2];
    float* out = (float*)d_out;

    const int rows = in_sizes[0] / 4096;   // 8192
    float* row_wbce   = (float*)d_ws;
    int*   row_streak = (int*)((char*)d_ws + (size_t)rows * sizeof(float));

    row_kernel<<<rows, 256, 0, stream>>>(yp, yt, dw, row_wbce, row_streak);
    finalize_kernel<<<1, 1024, 0, stream>>>(row_wbce, row_streak, rows, out);
}